// Round 2
// 202.761 us; speedup vs baseline: 1.0703x; 1.0703x over previous
//
#include <hip/hip_runtime.h>
#include <hip/hip_bf16.h>

typedef unsigned short u16;
typedef __attribute__((ext_vector_type(8))) short bf16x8;
typedef __attribute__((ext_vector_type(4))) float f32x4;

#define SEQ_L 4096
#define M_TOT 16384   // B*L

__device__ __forceinline__ float bf2f(u16 x) {
    unsigned u = ((unsigned)x) << 16;
    return __builtin_bit_cast(float, u);
}
__device__ __forceinline__ u16 f2bf(float f) {
    unsigned u = __builtin_bit_cast(unsigned, f);
    u += 0x7FFFu + ((u >> 16) & 1u);   // round-to-nearest-even
    return (u16)(u >> 16);
}
// async 16B global->LDS (direct-to-LDS DMA; LDS dest = wave-uniform base + lane*16)
__device__ __forceinline__ void gload16(const u16* g, u16* l) {
    __builtin_amdgcn_global_load_lds(
        (const __attribute__((address_space(1))) unsigned int*)g,
        (__attribute__((address_space(3))) unsigned int*)l, 16, 0, 0);
}

// ---- prep_all: pack six fp32 inputs -> x bf16 | Wqkv,Wout -> bf16 | mask -> u64 bitmap ----
__global__ __launch_bounds__(256) void prep_all(
    const float* __restrict__ in0, const float* __restrict__ in1, const float* __restrict__ in2,
    const float* __restrict__ in3, const float* __restrict__ in4, const float* __restrict__ in5,
    const float* __restrict__ Wqkv, const float* __restrict__ Wout, const void* __restrict__ mask,
    u16* __restrict__ x, u16* __restrict__ Wqkv_bf, u16* __restrict__ Wout_bf,
    unsigned long long* __restrict__ bmap) {
    int id = blockIdx.x * 256 + threadIdx.x;
    if (id < 1572864) {
        const float* ins[6] = {in0, in1, in2, in3, in4, in5};
        int which = id >> 18, j = id & 262143;
        int m = j >> 4, c8 = j & 15;
        const float* sp = ins[which] + (size_t)m * 128 + c8 * 8;
        float4 a = *(const float4*)sp;
        float4 b = *(const float4*)(sp + 4);
        u16 t[8] = {f2bf(a.x), f2bf(a.y), f2bf(a.z), f2bf(a.w),
                    f2bf(b.x), f2bf(b.y), f2bf(b.z), f2bf(b.w)};
        *(uint4*)(x + (size_t)m * 768 + which * 128 + c8 * 8) = *(uint4*)t;
    } else if (id < 1572864 + 73728 + 8192) {
        int i = id - 1572864;
        const float* src = (i < 73728) ? Wqkv : Wout;
        u16* dst = (i < 73728) ? Wqkv_bf : Wout_bf;
        if (i >= 73728) i -= 73728;
        const float* sp = src + (size_t)i * 8;
        float4 a = *(const float4*)sp;
        float4 b = *(const float4*)(sp + 4);
        u16 t[8] = {f2bf(a.x), f2bf(a.y), f2bf(a.z), f2bf(a.w),
                    f2bf(b.x), f2bf(b.y), f2bf(b.z), f2bf(b.w)};
        *(uint4*)(dst + (size_t)i * 8) = *(uint4*)t;
    } else if (id < 1572864 + 73728 + 8192 + 4096) {
        int i = id - 1572864 - 73728 - 8192;   // wave-aligned: one wave = one mask row
        int bi = i >> 6, bj = i & 63;
        size_t e = (size_t)(bi * 64) * SEQ_L + (size_t)bj * 64;
        const unsigned char* p8 = (const unsigned char*)mask;
        unsigned w0 = *(const unsigned*)mask;   // [0][0],[0][1] always true -> fingerprint
        bool v;
        if (w0 == 0x01010101u || w0 == 0xFFFFFFFFu)      v = p8[e] != 0;
        else if (w0 == 0x3F803F80u || w0 == 0x3C003C00u) v = ((const u16*)mask)[e] != 0;
        else                                             v = ((const unsigned*)mask)[e] != 0;
        unsigned long long bits = __ballot(v);
        if ((i & 63) == 0) bmap[bi] = bits;
    }
}

// ---------------- QKV GEMM, 128x64 tile (grid 1536) ----------------
__global__ __launch_bounds__(256, 4) void qkv_gemm(
    const u16* __restrict__ X, const u16* __restrict__ W, const float* __restrict__ bias,
    u16* __restrict__ qk, u16* __restrict__ vt) {
    __shared__ __align__(16) u16 As[128 * 64];
    __shared__ __align__(16) u16 Bs[64 * 64];
    int m0 = blockIdx.x * 128, n0 = blockIdx.y * 64;
    int tid = threadIdx.x, lane = tid & 63, w = tid >> 6;
    int ln = lane & 15, quad = lane >> 4;
    int rw = (w >> 1) * 64, cw = (w & 1) * 32;
    int lr8 = lane >> 3, lc = lane & 7;
    f32x4 acc[4][2] = {};
    for (int kk = 0; kk < 768; kk += 64) {
        __syncthreads();
        #pragma unroll
        for (int j = 0; j < 4; j++) {
            int r0 = w * 32 + j * 8, r = r0 + lr8;
            gload16(X + (size_t)(m0 + r) * 768 + kk + ((lc ^ (r & 7)) * 8), As + r0 * 64 + lane * 8);
        }
        #pragma unroll
        for (int j = 0; j < 2; j++) {
            int r0 = w * 16 + j * 8, r = r0 + lr8;
            gload16(W + (size_t)(n0 + r) * 768 + kk + ((lc ^ (r & 7)) * 8), Bs + r0 * 64 + lane * 8);
        }
        __syncthreads();
        #pragma unroll
        for (int s = 0; s < 2; s++) {
            bf16x8 af[4], bfr[2];
            #pragma unroll
            for (int i = 0; i < 4; i++) {
                int R = rw + i * 16 + ln;
                af[i] = *(const bf16x8*)(As + R * 64 + ((4 * s + quad) ^ (ln & 7)) * 8);
            }
            #pragma unroll
            for (int t = 0; t < 2; t++) {
                int R = cw + t * 16 + ln;
                bfr[t] = *(const bf16x8*)(Bs + R * 64 + ((4 * s + quad) ^ (ln & 7)) * 8);
            }
            #pragma unroll
            for (int i = 0; i < 4; i++)
                #pragma unroll
                for (int t = 0; t < 2; t++)
                    acc[i][t] = __builtin_amdgcn_mfma_f32_16x16x32_bf16(af[i], bfr[t], acc[i][t], 0, 0, 0);
        }
    }
    #pragma unroll
    for (int i = 0; i < 4; i++) {
        int row0 = m0 + rw + i * 16 + 4 * quad;
        #pragma unroll
        for (int t = 0; t < 2; t++) {
            int col = n0 + cw + t * 16 + ln;
            float bv = bias[col];
            if (col < 512) {   // block-uniform (n0 is 64-aligned)
                #pragma unroll
                for (int r = 0; r < 4; r++)
                    qk[(size_t)(row0 + r) * 512 + col] = f2bf(acc[i][t][r] + bv);
            } else {
                int d = col - 512;
                int b = row0 >> 12, seq = row0 & 4095;
                u16 pk[4] = {f2bf(acc[i][t][0] + bv), f2bf(acc[i][t][1] + bv),
                             f2bf(acc[i][t][2] + bv), f2bf(acc[i][t][3] + bv)};
                *(ushort4*)(vt + ((size_t)(b * 2 + (d >> 7)) * 128 + (d & 127)) * SEQ_L + seq)
                    = *(ushort4*)pk;
            }
        }
    }
}

// ---- block-sparse flash attention, v2: block-cooperative shared staging ----
// Block = (qi, b, ch); 4 waves = 4 row-quarters of the same 64-row q-block.
// All 4 waves share ONE 64x128 K tile + ONE 128x64 V^T tile per key-block,
// double-buffered in LDS with cross-kb prefetch (counted vmcnt(8), never a
// mid-iteration drain). Waves have identical bmap rows -> uniform trip count,
// so two raw s_barriers per kb are race-free. Row-sum shfl reduce is replaced
// by a ones-column MFMA (accL rescales with alpha alongside O for free); the
// 4 row-max shfl chains are interleaved for ILP.
__global__ __launch_bounds__(256, 2) void attn_sparse(
    const u16* __restrict__ qk, const u16* __restrict__ vt,
    const unsigned long long* __restrict__ bmap, u16* __restrict__ attn_bf) {
    __shared__ __align__(16) u16 Ks[2][64 * 128];   // 32 KB (double-buffered)
    __shared__ __align__(16) u16 Vs[2][128 * 64];   // 32 KB (double-buffered)
    __shared__ __align__(16) u16 Psm[4][16 * 72];   // 9 KB  (per-wave P scratch)

    int lane = threadIdx.x & 63, w = threadIdx.x >> 6;
    int ln = lane & 15, quad = lane >> 4;
    int u = blockIdx.x >> 3, v = blockIdx.x & 7;
    int qi = (u < 32) ? (63 - u) : (u - 32);    // heavy qi dispatched first
    int b = v >> 1, ch = v & 1;
    int rowbase = b * SEQ_L + qi * 64 + w * 16; // quarter = wave id
    const float scale = 0.08838834764831845f;   // 1/sqrt(128)
    u16* Ps = Psm[w];

    // Q fragments: A[m=ln][k=32s+8*quad+j]
    bf16x8 qf[4];
    {
        const u16* qp = qk + (size_t)(rowbase + ln) * 512 + ch * 128;
        #pragma unroll
        for (int s = 0; s < 4; s++) qf[s] = *(const bf16x8*)(qp + 32 * s + 8 * quad);
    }
    bf16x8 onesb;
    #pragma unroll
    for (int j = 0; j < 8; j++) onesb[j] = (short)0x3F80;   // bf16 1.0

    float m_st[4];
    #pragma unroll
    for (int r = 0; r < 4; r++) m_st[r] = -1e30f;
    f32x4 accO[8] = {};
    f32x4 accL = {};

    const u16* kbase0 = qk + (size_t)b * SEQ_L * 512 + 256 + ch * 128;
    const u16* vbase0 = vt + (size_t)(b * 2 + ch) * 128 * SEQ_L;
    unsigned long long bm = bmap[qi];           // tril: bits > qi are already 0

    // prologue: stage first key-block into buffer 0 (8 gload16 per thread)
    int kb = __ffsll(bm) - 1; bm &= bm - 1;
    {
        const u16* kp = kbase0 + (size_t)(kb * 64) * 512;
        const u16* vp = vbase0 + kb * 64;
        #pragma unroll
        for (int j = 0; j < 4; j++) {           // K: wave w stages rows w*16..w*16+15
            int kr = w * 16 + j * 4 + (lane >> 4);
            gload16(kp + (size_t)kr * 512 + (((lane & 15) ^ (kr & 7)) * 8),
                    Ks[0] + (w * 16 + j * 4) * 128 + lane * 8);
        }
        #pragma unroll
        for (int j = 0; j < 4; j++) {           // V^T: wave w stages d-rows w*32..w*32+31
            int d = w * 32 + j * 8 + (lane >> 3);
            gload16(vp + (size_t)d * SEQ_L + (((lane & 7) ^ (d & 7)) * 8),
                    Vs[0] + (w * 32 + j * 8) * 64 + lane * 8);
        }
    }

    int bufc = 0;
    while (true) {
        // prefetch next key-block into the other buffer (safe: last compute on
        // that buffer was fenced by the end-of-iteration barrier)
        int nkb = -1;
        if (bm) {
            nkb = __ffsll(bm) - 1; bm &= bm - 1;
            const u16* kp = kbase0 + (size_t)(nkb * 64) * 512;
            const u16* vp = vbase0 + nkb * 64;
            u16* Kd = Ks[bufc ^ 1];
            u16* Vd = Vs[bufc ^ 1];
            #pragma unroll
            for (int j = 0; j < 4; j++) {
                int kr = w * 16 + j * 4 + (lane >> 4);
                gload16(kp + (size_t)kr * 512 + (((lane & 15) ^ (kr & 7)) * 8),
                        Kd + (w * 16 + j * 4) * 128 + lane * 8);
            }
            #pragma unroll
            for (int j = 0; j < 4; j++) {
                int d = w * 32 + j * 8 + (lane >> 3);
                gload16(vp + (size_t)d * SEQ_L + (((lane & 7) ^ (d & 7)) * 8),
                        Vd + (w * 32 + j * 8) * 64 + lane * 8);
            }
        }
        // counted wait: 8 prefetch loads stay in flight; my current-tile loads done
        if (nkb >= 0) __builtin_amdgcn_s_waitcnt(0x0F78);   // vmcnt(8)
        else          __builtin_amdgcn_s_waitcnt(0x0F70);   // vmcnt(0)
        __builtin_amdgcn_s_barrier();           // everyone's staging landed

        const u16* K = Ks[bufc];
        const u16* V = Vs[bufc];

        // S = Q K^T over 64 keys: D[m=4*quad+r][n=16t+ln]
        f32x4 accS[4] = {};
        #pragma unroll
        for (int s = 0; s < 4; s++)
            #pragma unroll
            for (int t = 0; t < 4; t++) {
                bf16x8 kf = *(const bf16x8*)(K + (t * 16 + ln) * 128 +
                                             (((4 * s + quad) ^ (ln & 7)) * 8));
                accS[t] = __builtin_amdgcn_mfma_f32_16x16x32_bf16(qf[s], kf, accS[t], 0, 0, 0);
            }

        // online softmax: 4 interleaved max-reduce chains (16-lane groups)
        float mx[4];
        #pragma unroll
        for (int r = 0; r < 4; r++)
            mx[r] = fmaxf(fmaxf(accS[0][r], accS[1][r]),
                          fmaxf(accS[2][r], accS[3][r])) * scale;
        #pragma unroll
        for (int off = 1; off < 16; off <<= 1) {
            float t0 = __shfl_xor(mx[0], off, 64);
            float t1 = __shfl_xor(mx[1], off, 64);
            float t2 = __shfl_xor(mx[2], off, 64);
            float t3 = __shfl_xor(mx[3], off, 64);
            mx[0] = fmaxf(mx[0], t0); mx[1] = fmaxf(mx[1], t1);
            mx[2] = fmaxf(mx[2], t2); mx[3] = fmaxf(mx[3], t3);
        }
        float alpha[4];
        #pragma unroll
        for (int r = 0; r < 4; r++) {
            float nm = fmaxf(m_st[r], mx[r]);
            alpha[r] = __expf(m_st[r] - nm);
            m_st[r] = nm;
        }
        #pragma unroll
        for (int r = 0; r < 4; r++)
            #pragma unroll
            for (int t = 0; t < 4; t++)
                Ps[(4 * quad + r) * 72 + t * 16 + ln] =
                    f2bf(__expf(accS[t][r] * scale - m_st[r]));
        #pragma unroll
        for (int nt = 0; nt < 8; nt++)
            #pragma unroll
            for (int r = 0; r < 4; r++) accO[nt][r] *= alpha[r];
        #pragma unroll
        for (int r = 0; r < 4; r++) accL[r] *= alpha[r];

        // O += P V ; l += P·1 (ones-column MFMA replaces the shfl row-sum)
        #pragma unroll
        for (int h = 0; h < 2; h++) {
            bf16x8 pf = *(const bf16x8*)(Ps + ln * 72 + h * 32 + 8 * quad);
            accL = __builtin_amdgcn_mfma_f32_16x16x32_bf16(pf, onesb, accL, 0, 0, 0);
            #pragma unroll
            for (int nt = 0; nt < 8; nt++) {
                bf16x8 vf = *(const bf16x8*)(V + (nt * 16 + ln) * 64 +
                                             (((4 * h + quad) ^ (ln & 7)) * 8));
                accO[nt] = __builtin_amdgcn_mfma_f32_16x16x32_bf16(pf, vf, accO[nt], 0, 0, 0);
            }
        }

        if (nkb < 0) break;
        __builtin_amdgcn_s_barrier();           // all reads of bufc done -> reusable
        bufc ^= 1;
    }

    // epilogue: attn_bf[row][ch*128 + col] = O / l   (l lives in accL, any ln)
    float inv[4];
    #pragma unroll
    for (int r = 0; r < 4; r++) inv[r] = 1.0f / fmaxf(accL[r], 1e-20f);
    #pragma unroll
    for (int nt = 0; nt < 8; nt++)
        #pragma unroll
        for (int r = 0; r < 4; r++)
            attn_bf[(size_t)(rowbase + 4 * quad + r) * 256 + ch * 128 + nt * 16 + ln]
                = f2bf(accO[nt][r] * inv[r]);
}

// ---------------- out projection: attn[16384,256](bf16) @ Wout^T + b -> fp32 halves ----------------
__global__ __launch_bounds__(256) void out_gemm(
    const u16* __restrict__ A, const u16* __restrict__ W, const float* __restrict__ bias,
    float* __restrict__ out) {
    __shared__ __align__(16) u16 As[64 * 64];
    __shared__ __align__(16) u16 Bs[64 * 64];
    int m0 = blockIdx.x * 64, n0 = blockIdx.y * 64;
    int tid = threadIdx.x, lane = tid & 63, w = tid >> 6;
    int ln = lane & 15, quad = lane >> 4;
    int lr8 = lane >> 3, lc = lane & 7;
    int swz_st = lc ^ (lr8 & 7);
    f32x4 acc[4] = {};
    for (int kk = 0; kk < 256; kk += 64) {
        __syncthreads();
        #pragma unroll
        for (int j = 0; j < 2; j++) {
            int r0 = w * 16 + j * 8;
            int r = r0 + lr8;
            gload16(A + (size_t)(m0 + r) * 256 + kk + swz_st * 8, As + r0 * 64 + lane * 8);
            gload16(W + (size_t)(n0 + r) * 256 + kk + swz_st * 8, Bs + r0 * 64 + lane * 8);
        }
        __syncthreads();
        #pragma unroll
        for (int s = 0; s < 2; s++) {
            int R = w * 16 + ln;
            bf16x8 af = *(const bf16x8*)(As + R * 64 + ((4 * s + quad) ^ (ln & 7)) * 8);
            #pragma unroll
            for (int t = 0; t < 4; t++) {
                int Rb = t * 16 + ln;
                bf16x8 bfr = *(const bf16x8*)(Bs + Rb * 64 + ((4 * s + quad) ^ (ln & 7)) * 8);
                acc[t] = __builtin_amdgcn_mfma_f32_16x16x32_bf16(af, bfr, acc[t], 0, 0, 0);
            }
        }
    }
    const size_t half = (size_t)M_TOT * 128;
    #pragma unroll
    for (int t = 0; t < 4; t++) {
        int col = n0 + t * 16 + ln;
        float bv = bias[col];
        float* base = (col < 128) ? (out + col) : (out + half + (col - 128));
        #pragma unroll
        for (int r = 0; r < 4; r++) {
            int row = m0 + w * 16 + 4 * quad + r;
            base[(size_t)row * 128] = acc[t][r] + bv;
        }
    }
}

extern "C" void kernel_launch(void* const* d_in, const int* in_sizes, int n_in,
                              void* d_out, int out_size, void* d_ws, size_t ws_size,
                              hipStream_t stream) {
    char* ws = (char*)d_ws;
    u16* x_bf    = (u16*)ws;                          // 16384*768  = 25.2 MB
    u16* qk_buf  = x_bf + (size_t)M_TOT * 768;        // 16384*512  = 16.8 MB
    u16* vt_buf  = qk_buf + (size_t)M_TOT * 512;      // 1024*4096  =  8.4 MB
    u16* attn_bf = vt_buf + (size_t)1024 * SEQ_L;     // 16384*256  =  8.4 MB
    u16* Wqkv_bf = attn_bf + (size_t)M_TOT * 256;     // 589824
    u16* Wout_bf = Wqkv_bf + 589824;                  // 65536
    unsigned long long* bmap = (unsigned long long*)(Wout_bf + 65536);   // 64 x u64

    hipLaunchKernelGGL(prep_all, dim3(6480), dim3(256), 0, stream,
                       (const float*)d_in[0], (const float*)d_in[1], (const float*)d_in[2],
                       (const float*)d_in[3], (const float*)d_in[4], (const float*)d_in[5],
                       (const float*)d_in[6], (const float*)d_in[8], d_in[10],
                       x_bf, Wqkv_bf, Wout_bf, bmap);
    hipLaunchKernelGGL(qkv_gemm, dim3(128, 12), dim3(256), 0, stream,
                       x_bf, Wqkv_bf, (const float*)d_in[7], qk_buf, vt_buf);
    hipLaunchKernelGGL(attn_sparse, dim3(512), dim3(256), 0, stream,
                       qk_buf, vt_buf, bmap, attn_bf);
    hipLaunchKernelGGL(out_gemm, dim3(256, 4), dim3(256), 0, stream,
                       attn_bf, Wout_bf, (const float*)d_in[9], (float*)d_out);
}

// Round 3
// 195.591 us; speedup vs baseline: 1.1095x; 1.0367x over previous
//
#include <hip/hip_runtime.h>
#include <hip/hip_bf16.h>

typedef unsigned short u16;
typedef __attribute__((ext_vector_type(8))) short bf16x8;
typedef __attribute__((ext_vector_type(4))) float f32x4;

#define SEQ_L 4096
#define M_TOT 16384   // B*L

__device__ __forceinline__ float bf2f(u16 x) {
    unsigned u = ((unsigned)x) << 16;
    return __builtin_bit_cast(float, u);
}
__device__ __forceinline__ u16 f2bf(float f) {
    unsigned u = __builtin_bit_cast(unsigned, f);
    u += 0x7FFFu + ((u >> 16) & 1u);   // round-to-nearest-even
    return (u16)(u >> 16);
}
// async 16B global->LDS (direct-to-LDS DMA; LDS dest = wave-uniform base + lane*16)
__device__ __forceinline__ void gload16(const u16* g, u16* l) {
    __builtin_amdgcn_global_load_lds(
        (const __attribute__((address_space(1))) unsigned int*)g,
        (__attribute__((address_space(3))) unsigned int*)l, 16, 0, 0);
}

// ---- prep_all: pack six fp32 inputs -> x bf16 | Wqkv,Wout -> bf16 | mask -> u64 bitmap ----
__global__ __launch_bounds__(256) void prep_all(
    const float* __restrict__ in0, const float* __restrict__ in1, const float* __restrict__ in2,
    const float* __restrict__ in3, const float* __restrict__ in4, const float* __restrict__ in5,
    const float* __restrict__ Wqkv, const float* __restrict__ Wout, const void* __restrict__ mask,
    u16* __restrict__ x, u16* __restrict__ Wqkv_bf, u16* __restrict__ Wout_bf,
    unsigned long long* __restrict__ bmap) {
    int id = blockIdx.x * 256 + threadIdx.x;
    if (id < 1572864) {
        const float* ins[6] = {in0, in1, in2, in3, in4, in5};
        int which = id >> 18, j = id & 262143;
        int m = j >> 4, c8 = j & 15;
        const float* sp = ins[which] + (size_t)m * 128 + c8 * 8;
        float4 a = *(const float4*)sp;
        float4 b = *(const float4*)(sp + 4);
        u16 t[8] = {f2bf(a.x), f2bf(a.y), f2bf(a.z), f2bf(a.w),
                    f2bf(b.x), f2bf(b.y), f2bf(b.z), f2bf(b.w)};
        *(uint4*)(x + (size_t)m * 768 + which * 128 + c8 * 8) = *(uint4*)t;
    } else if (id < 1572864 + 73728 + 8192) {
        int i = id - 1572864;
        const float* src = (i < 73728) ? Wqkv : Wout;
        u16* dst = (i < 73728) ? Wqkv_bf : Wout_bf;
        if (i >= 73728) i -= 73728;
        const float* sp = src + (size_t)i * 8;
        float4 a = *(const float4*)sp;
        float4 b = *(const float4*)(sp + 4);
        u16 t[8] = {f2bf(a.x), f2bf(a.y), f2bf(a.z), f2bf(a.w),
                    f2bf(b.x), f2bf(b.y), f2bf(b.z), f2bf(b.w)};
        *(uint4*)(dst + (size_t)i * 8) = *(uint4*)t;
    } else if (id < 1572864 + 73728 + 8192 + 4096) {
        int i = id - 1572864 - 73728 - 8192;   // wave-aligned: one wave = one mask row
        int bi = i >> 6, bj = i & 63;
        size_t e = (size_t)(bi * 64) * SEQ_L + (size_t)bj * 64;
        const unsigned char* p8 = (const unsigned char*)mask;
        unsigned w0 = *(const unsigned*)mask;   // [0][0],[0][1] always true -> fingerprint
        bool v;
        if (w0 == 0x01010101u || w0 == 0xFFFFFFFFu)      v = p8[e] != 0;
        else if (w0 == 0x3F803F80u || w0 == 0x3C003C00u) v = ((const u16*)mask)[e] != 0;
        else                                             v = ((const unsigned*)mask)[e] != 0;
        unsigned long long bits = __ballot(v);
        if ((i & 63) == 0) bmap[bi] = bits;
    }
}

// ---------------- QKV GEMM, 128x128 tile (grid 128x6 = 768 = 3 blocks/CU) ----------------
// m97 structure: 4 waves, each owns a 64x64 sub-tile (4x4 f32x4 acc), BK=64,
// XOR-swizzled global_load_lds staging, 32 MFMAs per wave per K-step.
__global__ __launch_bounds__(256, 3) void qkv_gemm(
    const u16* __restrict__ X, const u16* __restrict__ W, const float* __restrict__ bias,
    u16* __restrict__ qk, u16* __restrict__ vt) {
    __shared__ __align__(16) u16 As[128 * 64];
    __shared__ __align__(16) u16 Bs[128 * 64];
    int m0 = blockIdx.x * 128, n0 = blockIdx.y * 128;
    int tid = threadIdx.x, lane = tid & 63, w = tid >> 6;
    int ln = lane & 15, quad = lane >> 4;
    int rw = (w >> 1) * 64, cw = (w & 1) * 64;
    int lr8 = lane >> 3, lc = lane & 7;
    f32x4 acc[4][4] = {};
    for (int kk = 0; kk < 768; kk += 64) {
        __syncthreads();
        #pragma unroll
        for (int j = 0; j < 4; j++) {
            int r0 = w * 32 + j * 8, r = r0 + lr8;
            gload16(X + (size_t)(m0 + r) * 768 + kk + ((lc ^ (r & 7)) * 8), As + r0 * 64 + lane * 8);
            gload16(W + (size_t)(n0 + r) * 768 + kk + ((lc ^ (r & 7)) * 8), Bs + r0 * 64 + lane * 8);
        }
        __syncthreads();
        #pragma unroll
        for (int s = 0; s < 2; s++) {
            bf16x8 af[4], bfr[4];
            #pragma unroll
            for (int i = 0; i < 4; i++) {
                int R = rw + i * 16 + ln;
                af[i] = *(const bf16x8*)(As + R * 64 + ((4 * s + quad) ^ (ln & 7)) * 8);
            }
            #pragma unroll
            for (int t = 0; t < 4; t++) {
                int R = cw + t * 16 + ln;
                bfr[t] = *(const bf16x8*)(Bs + R * 64 + ((4 * s + quad) ^ (ln & 7)) * 8);
            }
            #pragma unroll
            for (int i = 0; i < 4; i++)
                #pragma unroll
                for (int t = 0; t < 4; t++)
                    acc[i][t] = __builtin_amdgcn_mfma_f32_16x16x32_bf16(af[i], bfr[t], acc[i][t], 0, 0, 0);
        }
    }
    if (n0 < 512) {   // entire block writes qk (512 is 128-aligned -> uniform)
        #pragma unroll
        for (int i = 0; i < 4; i++) {
            int row0 = m0 + rw + i * 16 + 4 * quad;
            #pragma unroll
            for (int t = 0; t < 4; t++) {
                int col = n0 + cw + t * 16 + ln;
                float bv = bias[col];
                #pragma unroll
                for (int r = 0; r < 4; r++)
                    qk[(size_t)(row0 + r) * 512 + col] = f2bf(acc[i][t][r] + bv);
            }
        }
    } else {          // entire block writes vt (transposed V, per batch-channel)
        #pragma unroll
        for (int i = 0; i < 4; i++) {
            int row0 = m0 + rw + i * 16 + 4 * quad;
            int b = row0 >> 12, seq = row0 & 4095;
            #pragma unroll
            for (int t = 0; t < 4; t++) {
                int col = n0 + cw + t * 16 + ln;
                float bv = bias[col];
                int d = col - 512;
                u16 pk[4] = {f2bf(acc[i][t][0] + bv), f2bf(acc[i][t][1] + bv),
                             f2bf(acc[i][t][2] + bv), f2bf(acc[i][t][3] + bv)};
                *(ushort4*)(vt + ((size_t)(b * 2 + (d >> 7)) * 128 + (d & 127)) * SEQ_L + seq)
                    = *(ushort4*)pk;
            }
        }
    }
}

// ---- block-sparse flash attention, v2: block-cooperative shared staging ----
// Block = (qi, b, ch); 4 waves = 4 row-quarters of the same 64-row q-block.
// All 4 waves share ONE 64x128 K tile + ONE 128x64 V^T tile per key-block,
// double-buffered in LDS with cross-kb prefetch (counted vmcnt(8), never a
// mid-iteration drain). Waves have identical bmap rows -> uniform trip count,
// so two raw s_barriers per kb are race-free. Row-sum shfl reduce is replaced
// by a ones-column MFMA (accL rescales with alpha alongside O for free); the
// 4 row-max shfl chains are interleaved for ILP.
__global__ __launch_bounds__(256, 2) void attn_sparse(
    const u16* __restrict__ qk, const u16* __restrict__ vt,
    const unsigned long long* __restrict__ bmap, u16* __restrict__ attn_bf) {
    __shared__ __align__(16) u16 Ks[2][64 * 128];   // 32 KB (double-buffered)
    __shared__ __align__(16) u16 Vs[2][128 * 64];   // 32 KB (double-buffered)
    __shared__ __align__(16) u16 Psm[4][16 * 72];   // 9 KB  (per-wave P scratch)

    int lane = threadIdx.x & 63, w = threadIdx.x >> 6;
    int ln = lane & 15, quad = lane >> 4;
    int u = blockIdx.x >> 3, v = blockIdx.x & 7;
    int qi = (u < 32) ? (63 - u) : (u - 32);    // heavy qi dispatched first
    int b = v >> 1, ch = v & 1;
    int rowbase = b * SEQ_L + qi * 64 + w * 16; // quarter = wave id
    const float scale = 0.08838834764831845f;   // 1/sqrt(128)
    u16* Ps = Psm[w];

    // Q fragments: A[m=ln][k=32s+8*quad+j]
    bf16x8 qf[4];
    {
        const u16* qp = qk + (size_t)(rowbase + ln) * 512 + ch * 128;
        #pragma unroll
        for (int s = 0; s < 4; s++) qf[s] = *(const bf16x8*)(qp + 32 * s + 8 * quad);
    }
    bf16x8 onesb;
    #pragma unroll
    for (int j = 0; j < 8; j++) onesb[j] = (short)0x3F80;   // bf16 1.0

    float m_st[4];
    #pragma unroll
    for (int r = 0; r < 4; r++) m_st[r] = -1e30f;
    f32x4 accO[8] = {};
    f32x4 accL = {};

    const u16* kbase0 = qk + (size_t)b * SEQ_L * 512 + 256 + ch * 128;
    const u16* vbase0 = vt + (size_t)(b * 2 + ch) * 128 * SEQ_L;
    unsigned long long bm = bmap[qi];           // tril: bits > qi are already 0

    // prologue: stage first key-block into buffer 0 (8 gload16 per thread)
    int kb = __ffsll(bm) - 1; bm &= bm - 1;
    {
        const u16* kp = kbase0 + (size_t)(kb * 64) * 512;
        const u16* vp = vbase0 + kb * 64;
        #pragma unroll
        for (int j = 0; j < 4; j++) {           // K: wave w stages rows w*16..w*16+15
            int kr = w * 16 + j * 4 + (lane >> 4);
            gload16(kp + (size_t)kr * 512 + (((lane & 15) ^ (kr & 7)) * 8),
                    Ks[0] + (w * 16 + j * 4) * 128 + lane * 8);
        }
        #pragma unroll
        for (int j = 0; j < 4; j++) {           // V^T: wave w stages d-rows w*32..w*32+31
            int d = w * 32 + j * 8 + (lane >> 3);
            gload16(vp + (size_t)d * SEQ_L + (((lane & 7) ^ (d & 7)) * 8),
                    Vs[0] + (w * 32 + j * 8) * 64 + lane * 8);
        }
    }

    int bufc = 0;
    while (true) {
        // prefetch next key-block into the other buffer (safe: last compute on
        // that buffer was fenced by the end-of-iteration barrier)
        int nkb = -1;
        if (bm) {
            nkb = __ffsll(bm) - 1; bm &= bm - 1;
            const u16* kp = kbase0 + (size_t)(nkb * 64) * 512;
            const u16* vp = vbase0 + nkb * 64;
            u16* Kd = Ks[bufc ^ 1];
            u16* Vd = Vs[bufc ^ 1];
            #pragma unroll
            for (int j = 0; j < 4; j++) {
                int kr = w * 16 + j * 4 + (lane >> 4);
                gload16(kp + (size_t)kr * 512 + (((lane & 15) ^ (kr & 7)) * 8),
                        Kd + (w * 16 + j * 4) * 128 + lane * 8);
            }
            #pragma unroll
            for (int j = 0; j < 4; j++) {
                int d = w * 32 + j * 8 + (lane >> 3);
                gload16(vp + (size_t)d * SEQ_L + (((lane & 7) ^ (d & 7)) * 8),
                        Vd + (w * 32 + j * 8) * 64 + lane * 8);
            }
        }
        // counted wait: 8 prefetch loads stay in flight; my current-tile loads done
        if (nkb >= 0) __builtin_amdgcn_s_waitcnt(0x0F78);   // vmcnt(8)
        else          __builtin_amdgcn_s_waitcnt(0x0F70);   // vmcnt(0)
        __builtin_amdgcn_s_barrier();           // everyone's staging landed

        const u16* K = Ks[bufc];
        const u16* V = Vs[bufc];

        // S = Q K^T over 64 keys: D[m=4*quad+r][n=16t+ln]
        f32x4 accS[4] = {};
        #pragma unroll
        for (int s = 0; s < 4; s++)
            #pragma unroll
            for (int t = 0; t < 4; t++) {
                bf16x8 kf = *(const bf16x8*)(K + (t * 16 + ln) * 128 +
                                             (((4 * s + quad) ^ (ln & 7)) * 8));
                accS[t] = __builtin_amdgcn_mfma_f32_16x16x32_bf16(qf[s], kf, accS[t], 0, 0, 0);
            }

        // online softmax: 4 interleaved max-reduce chains (16-lane groups)
        float mx[4];
        #pragma unroll
        for (int r = 0; r < 4; r++)
            mx[r] = fmaxf(fmaxf(accS[0][r], accS[1][r]),
                          fmaxf(accS[2][r], accS[3][r])) * scale;
        #pragma unroll
        for (int off = 1; off < 16; off <<= 1) {
            float t0 = __shfl_xor(mx[0], off, 64);
            float t1 = __shfl_xor(mx[1], off, 64);
            float t2 = __shfl_xor(mx[2], off, 64);
            float t3 = __shfl_xor(mx[3], off, 64);
            mx[0] = fmaxf(mx[0], t0); mx[1] = fmaxf(mx[1], t1);
            mx[2] = fmaxf(mx[2], t2); mx[3] = fmaxf(mx[3], t3);
        }
        float alpha[4];
        #pragma unroll
        for (int r = 0; r < 4; r++) {
            float nm = fmaxf(m_st[r], mx[r]);
            alpha[r] = __expf(m_st[r] - nm);
            m_st[r] = nm;
        }
        #pragma unroll
        for (int r = 0; r < 4; r++)
            #pragma unroll
            for (int t = 0; t < 4; t++)
                Ps[(4 * quad + r) * 72 + t * 16 + ln] =
                    f2bf(__expf(accS[t][r] * scale - m_st[r]));
        #pragma unroll
        for (int nt = 0; nt < 8; nt++)
            #pragma unroll
            for (int r = 0; r < 4; r++) accO[nt][r] *= alpha[r];
        #pragma unroll
        for (int r = 0; r < 4; r++) accL[r] *= alpha[r];

        // O += P V ; l += P·1 (ones-column MFMA replaces the shfl row-sum)
        #pragma unroll
        for (int h = 0; h < 2; h++) {
            bf16x8 pf = *(const bf16x8*)(Ps + ln * 72 + h * 32 + 8 * quad);
            accL = __builtin_amdgcn_mfma_f32_16x16x32_bf16(pf, onesb, accL, 0, 0, 0);
            #pragma unroll
            for (int nt = 0; nt < 8; nt++) {
                bf16x8 vf = *(const bf16x8*)(V + (nt * 16 + ln) * 64 +
                                             (((4 * h + quad) ^ (ln & 7)) * 8));
                accO[nt] = __builtin_amdgcn_mfma_f32_16x16x32_bf16(pf, vf, accO[nt], 0, 0, 0);
            }
        }

        if (nkb < 0) break;
        __builtin_amdgcn_s_barrier();           // all reads of bufc done -> reusable
        bufc ^= 1;
    }

    // epilogue: attn_bf[row][ch*128 + col] = O / l   (l lives in accL, any ln)
    float inv[4];
    #pragma unroll
    for (int r = 0; r < 4; r++) inv[r] = 1.0f / fmaxf(accL[r], 1e-20f);
    #pragma unroll
    for (int nt = 0; nt < 8; nt++)
        #pragma unroll
        for (int r = 0; r < 4; r++)
            attn_bf[(size_t)(rowbase + 4 * quad + r) * 256 + ch * 128 + nt * 16 + ln]
                = f2bf(accO[nt][r] * inv[r]);
}

// ---------------- out projection: attn[16384,256](bf16) @ Wout^T + b -> fp32 halves ----------------
__global__ __launch_bounds__(256) void out_gemm(
    const u16* __restrict__ A, const u16* __restrict__ W, const float* __restrict__ bias,
    float* __restrict__ out) {
    __shared__ __align__(16) u16 As[64 * 64];
    __shared__ __align__(16) u16 Bs[64 * 64];
    int m0 = blockIdx.x * 64, n0 = blockIdx.y * 64;
    int tid = threadIdx.x, lane = tid & 63, w = tid >> 6;
    int ln = lane & 15, quad = lane >> 4;
    int lr8 = lane >> 3, lc = lane & 7;
    int swz_st = lc ^ (lr8 & 7);
    f32x4 acc[4] = {};
    for (int kk = 0; kk < 256; kk += 64) {
        __syncthreads();
        #pragma unroll
        for (int j = 0; j < 2; j++) {
            int r0 = w * 16 + j * 8;
            int r = r0 + lr8;
            gload16(A + (size_t)(m0 + r) * 256 + kk + swz_st * 8, As + r0 * 64 + lane * 8);
            gload16(W + (size_t)(n0 + r) * 256 + kk + swz_st * 8, Bs + r0 * 64 + lane * 8);
        }
        __syncthreads();
        #pragma unroll
        for (int s = 0; s < 2; s++) {
            int R = w * 16 + ln;
            bf16x8 af = *(const bf16x8*)(As + R * 64 + ((4 * s + quad) ^ (ln & 7)) * 8);
            #pragma unroll
            for (int t = 0; t < 4; t++) {
                int Rb = t * 16 + ln;
                bf16x8 bfr = *(const bf16x8*)(Bs + Rb * 64 + ((4 * s + quad) ^ (ln & 7)) * 8);
                acc[t] = __builtin_amdgcn_mfma_f32_16x16x32_bf16(af, bfr, acc[t], 0, 0, 0);
            }
        }
    }
    const size_t half = (size_t)M_TOT * 128;
    #pragma unroll
    for (int t = 0; t < 4; t++) {
        int col = n0 + t * 16 + ln;
        float bv = bias[col];
        float* base = (col < 128) ? (out + col) : (out + half + (col - 128));
        #pragma unroll
        for (int r = 0; r < 4; r++) {
            int row = m0 + w * 16 + 4 * quad + r;
            base[(size_t)row * 128] = acc[t][r] + bv;
        }
    }
}

extern "C" void kernel_launch(void* const* d_in, const int* in_sizes, int n_in,
                              void* d_out, int out_size, void* d_ws, size_t ws_size,
                              hipStream_t stream) {
    char* ws = (char*)d_ws;
    u16* x_bf    = (u16*)ws;                          // 16384*768  = 25.2 MB
    u16* qk_buf  = x_bf + (size_t)M_TOT * 768;        // 16384*512  = 16.8 MB
    u16* vt_buf  = qk_buf + (size_t)M_TOT * 512;      // 1024*4096  =  8.4 MB
    u16* attn_bf = vt_buf + (size_t)1024 * SEQ_L;     // 16384*256  =  8.4 MB
    u16* Wqkv_bf = attn_bf + (size_t)M_TOT * 256;     // 589824
    u16* Wout_bf = Wqkv_bf + 589824;                  // 65536
    unsigned long long* bmap = (unsigned long long*)(Wout_bf + 65536);   // 64 x u64

    hipLaunchKernelGGL(prep_all, dim3(6480), dim3(256), 0, stream,
                       (const float*)d_in[0], (const float*)d_in[1], (const float*)d_in[2],
                       (const float*)d_in[3], (const float*)d_in[4], (const float*)d_in[5],
                       (const float*)d_in[6], (const float*)d_in[8], d_in[10],
                       x_bf, Wqkv_bf, Wout_bf, bmap);
    hipLaunchKernelGGL(qkv_gemm, dim3(128, 6), dim3(256), 0, stream,
                       x_bf, Wqkv_bf, (const float*)d_in[7], qk_buf, vt_buf);
    hipLaunchKernelGGL(attn_sparse, dim3(512), dim3(256), 0, stream,
                       qk_buf, vt_buf, bmap, attn_bf);
    hipLaunchKernelGGL(out_gemm, dim3(256, 4), dim3(256), 0, stream,
                       attn_bf, Wout_bf, (const float*)d_in[9], (float*)d_out);
}

// Round 4
// 195.316 us; speedup vs baseline: 1.1111x; 1.0014x over previous
//
#include <hip/hip_runtime.h>
#include <hip/hip_bf16.h>

typedef unsigned short u16;
typedef __attribute__((ext_vector_type(8))) short bf16x8;
typedef __attribute__((ext_vector_type(4))) float f32x4;

#define SEQ_L 4096
#define M_TOT 16384   // B*L

__device__ __forceinline__ float bf2f(u16 x) {
    unsigned u = ((unsigned)x) << 16;
    return __builtin_bit_cast(float, u);
}
__device__ __forceinline__ u16 f2bf(float f) {
    unsigned u = __builtin_bit_cast(unsigned, f);
    u += 0x7FFFu + ((u >> 16) & 1u);   // round-to-nearest-even
    return (u16)(u >> 16);
}
// async 16B global->LDS (direct-to-LDS DMA; LDS dest = wave-uniform base + lane*16)
__device__ __forceinline__ void gload16(const u16* g, u16* l) {
    __builtin_amdgcn_global_load_lds(
        (const __attribute__((address_space(1))) unsigned int*)g,
        (__attribute__((address_space(3))) unsigned int*)l, 16, 0, 0);
}

// ---- prep_all: pack six fp32 inputs -> x bf16 | Wqkv,Wout -> bf16 | mask -> u64 bitmap ----
__global__ __launch_bounds__(256) void prep_all(
    const float* __restrict__ in0, const float* __restrict__ in1, const float* __restrict__ in2,
    const float* __restrict__ in3, const float* __restrict__ in4, const float* __restrict__ in5,
    const float* __restrict__ Wqkv, const float* __restrict__ Wout, const void* __restrict__ mask,
    u16* __restrict__ x, u16* __restrict__ Wqkv_bf, u16* __restrict__ Wout_bf,
    unsigned long long* __restrict__ bmap) {
    int id = blockIdx.x * 256 + threadIdx.x;
    if (id < 1572864) {
        const float* ins[6] = {in0, in1, in2, in3, in4, in5};
        int which = id >> 18, j = id & 262143;
        int m = j >> 4, c8 = j & 15;
        const float* sp = ins[which] + (size_t)m * 128 + c8 * 8;
        float4 a = *(const float4*)sp;
        float4 b = *(const float4*)(sp + 4);
        u16 t[8] = {f2bf(a.x), f2bf(a.y), f2bf(a.z), f2bf(a.w),
                    f2bf(b.x), f2bf(b.y), f2bf(b.z), f2bf(b.w)};
        *(uint4*)(x + (size_t)m * 768 + which * 128 + c8 * 8) = *(uint4*)t;
    } else if (id < 1572864 + 73728 + 8192) {
        int i = id - 1572864;
        const float* src = (i < 73728) ? Wqkv : Wout;
        u16* dst = (i < 73728) ? Wqkv_bf : Wout_bf;
        if (i >= 73728) i -= 73728;
        const float* sp = src + (size_t)i * 8;
        float4 a = *(const float4*)sp;
        float4 b = *(const float4*)(sp + 4);
        u16 t[8] = {f2bf(a.x), f2bf(a.y), f2bf(a.z), f2bf(a.w),
                    f2bf(b.x), f2bf(b.y), f2bf(b.z), f2bf(b.w)};
        *(uint4*)(dst + (size_t)i * 8) = *(uint4*)t;
    } else if (id < 1572864 + 73728 + 8192 + 4096) {
        int i = id - 1572864 - 73728 - 8192;   // wave-aligned: one wave = one mask row
        int bi = i >> 6, bj = i & 63;
        size_t e = (size_t)(bi * 64) * SEQ_L + (size_t)bj * 64;
        const unsigned char* p8 = (const unsigned char*)mask;
        unsigned w0 = *(const unsigned*)mask;   // [0][0],[0][1] always true -> fingerprint
        bool v;
        if (w0 == 0x01010101u || w0 == 0xFFFFFFFFu)      v = p8[e] != 0;
        else if (w0 == 0x3F803F80u || w0 == 0x3C003C00u) v = ((const u16*)mask)[e] != 0;
        else                                             v = ((const unsigned*)mask)[e] != 0;
        unsigned long long bits = __ballot(v);
        if ((i & 63) == 0) bmap[bi] = bits;
    }
}

// ---------------- QKV GEMM, 128x128 tile (grid 128x6 = 768 = 3 blocks/CU) ----------------
__global__ __launch_bounds__(256, 3) void qkv_gemm(
    const u16* __restrict__ X, const u16* __restrict__ W, const float* __restrict__ bias,
    u16* __restrict__ qk, u16* __restrict__ vt) {
    __shared__ __align__(16) u16 As[128 * 64];
    __shared__ __align__(16) u16 Bs[128 * 64];
    int m0 = blockIdx.x * 128, n0 = blockIdx.y * 128;
    int tid = threadIdx.x, lane = tid & 63, w = tid >> 6;
    int ln = lane & 15, quad = lane >> 4;
    int rw = (w >> 1) * 64, cw = (w & 1) * 64;
    int lr8 = lane >> 3, lc = lane & 7;
    f32x4 acc[4][4] = {};
    for (int kk = 0; kk < 768; kk += 64) {
        __syncthreads();
        #pragma unroll
        for (int j = 0; j < 4; j++) {
            int r0 = w * 32 + j * 8, r = r0 + lr8;
            gload16(X + (size_t)(m0 + r) * 768 + kk + ((lc ^ (r & 7)) * 8), As + r0 * 64 + lane * 8);
            gload16(W + (size_t)(n0 + r) * 768 + kk + ((lc ^ (r & 7)) * 8), Bs + r0 * 64 + lane * 8);
        }
        __syncthreads();
        #pragma unroll
        for (int s = 0; s < 2; s++) {
            bf16x8 af[4], bfr[4];
            #pragma unroll
            for (int i = 0; i < 4; i++) {
                int R = rw + i * 16 + ln;
                af[i] = *(const bf16x8*)(As + R * 64 + ((4 * s + quad) ^ (ln & 7)) * 8);
            }
            #pragma unroll
            for (int t = 0; t < 4; t++) {
                int R = cw + t * 16 + ln;
                bfr[t] = *(const bf16x8*)(Bs + R * 64 + ((4 * s + quad) ^ (ln & 7)) * 8);
            }
            #pragma unroll
            for (int i = 0; i < 4; i++)
                #pragma unroll
                for (int t = 0; t < 4; t++)
                    acc[i][t] = __builtin_amdgcn_mfma_f32_16x16x32_bf16(af[i], bfr[t], acc[i][t], 0, 0, 0);
        }
    }
    if (n0 < 512) {   // entire block writes qk (512 is 128-aligned -> uniform)
        #pragma unroll
        for (int i = 0; i < 4; i++) {
            int row0 = m0 + rw + i * 16 + 4 * quad;
            #pragma unroll
            for (int t = 0; t < 4; t++) {
                int col = n0 + cw + t * 16 + ln;
                float bv = bias[col];
                #pragma unroll
                for (int r = 0; r < 4; r++)
                    qk[(size_t)(row0 + r) * 512 + col] = f2bf(acc[i][t][r] + bv);
            }
        }
    } else {          // entire block writes vt (transposed V, per batch-channel)
        #pragma unroll
        for (int i = 0; i < 4; i++) {
            int row0 = m0 + rw + i * 16 + 4 * quad;
            int b = row0 >> 12, seq = row0 & 4095;
            #pragma unroll
            for (int t = 0; t < 4; t++) {
                int col = n0 + cw + t * 16 + ln;
                float bv = bias[col];
                int d = col - 512;
                u16 pk[4] = {f2bf(acc[i][t][0] + bv), f2bf(acc[i][t][1] + bv),
                             f2bf(acc[i][t][2] + bv), f2bf(acc[i][t][3] + bv)};
                *(ushort4*)(vt + ((size_t)(b * 2 + (d >> 7)) * 128 + (d & 127)) * SEQ_L + seq)
                    = *(ushort4*)pk;
            }
        }
    }
}

// ---- block-sparse flash attention, v3: swapped QK^T + fully in-register softmax ----
// Staging/sync identical to v2 (K,V dbuf, counted vmcnt, 2 barriers/iter).
// Compute side: S^T = mfma(K,Q) puts all 64 key-scores of q-row (q=ln) into the
// lane's quad-group -> max/sum = local 16-reduce + 2 shfl_xor (was 5 rounds x4);
// m,l are per-lane scalars; P packs to bf16 in-register and the PV A-fragment is
// built with 16 shfls + 8 selects (no LDS round-trip, no ones-MFMA, Psm freed).
__global__ __launch_bounds__(256, 2) void attn_sparse(
    const u16* __restrict__ qk, const u16* __restrict__ vt,
    const unsigned long long* __restrict__ bmap, u16* __restrict__ attn_bf) {
    __shared__ __align__(16) u16 Ks[2][64 * 128];   // 32 KB (double-buffered)
    __shared__ __align__(16) u16 Vs[2][128 * 64];   // 32 KB (double-buffered)

    int lane = threadIdx.x & 63, w = threadIdx.x >> 6;
    int ln = lane & 15, quad = lane >> 4;
    int u = blockIdx.x >> 3, v = blockIdx.x & 7;
    int qi = (u < 32) ? (63 - u) : (u - 32);    // heavy qi dispatched first
    int b = v >> 1, ch = v & 1;
    int rowbase = b * SEQ_L + qi * 64 + w * 16; // quarter = wave id
    const float scale = 0.08838834764831845f;   // 1/sqrt(128)

    // Q fragments (B-operand now; same layout): lane holds q-col ln, k=32s+8quad+j
    bf16x8 qf[4];
    {
        const u16* qp = qk + (size_t)(rowbase + ln) * 512 + ch * 128;
        #pragma unroll
        for (int s = 0; s < 4; s++) qf[s] = *(const bf16x8*)(qp + 32 * s + 8 * quad);
    }

    float m_st = -1e30f, l_st = 0.f;            // per-lane: q-row = ln
    f32x4 accO[8] = {};

    const u16* kbase0 = qk + (size_t)b * SEQ_L * 512 + 256 + ch * 128;
    const u16* vbase0 = vt + (size_t)(b * 2 + ch) * 128 * SEQ_L;
    unsigned long long bm = bmap[qi];           // tril: bits > qi are already 0

    // prologue: stage first key-block into buffer 0 (8+8 gload16 per thread)
    int kb = __ffsll(bm) - 1; bm &= bm - 1;
    {
        const u16* kp = kbase0 + (size_t)(kb * 64) * 512;
        const u16* vp = vbase0 + kb * 64;
        #pragma unroll
        for (int j = 0; j < 4; j++) {           // K: wave w stages rows w*16..w*16+15
            int kr = w * 16 + j * 4 + (lane >> 4);
            gload16(kp + (size_t)kr * 512 + (((lane & 15) ^ (kr & 7)) * 8),
                    Ks[0] + (w * 16 + j * 4) * 128 + lane * 8);
        }
        #pragma unroll
        for (int j = 0; j < 4; j++) {           // V^T: wave w stages d-rows w*32..w*32+31
            int d = w * 32 + j * 8 + (lane >> 3);
            gload16(vp + (size_t)d * SEQ_L + (((lane & 7) ^ (d & 7)) * 8),
                    Vs[0] + (w * 32 + j * 8) * 64 + lane * 8);
        }
    }

    int srcA = ln + ((quad & 1) << 5);          // source lanes for P-fragment build
    int srcB = srcA + 16;
    bool hi = (quad & 2) != 0;                  // selects t = 2h+1 vs 2h

    int bufc = 0;
    while (true) {
        // prefetch next key-block into the other buffer
        int nkb = -1;
        if (bm) {
            nkb = __ffsll(bm) - 1; bm &= bm - 1;
            const u16* kp = kbase0 + (size_t)(nkb * 64) * 512;
            const u16* vp = vbase0 + nkb * 64;
            u16* Kd = Ks[bufc ^ 1];
            u16* Vd = Vs[bufc ^ 1];
            #pragma unroll
            for (int j = 0; j < 4; j++) {
                int kr = w * 16 + j * 4 + (lane >> 4);
                gload16(kp + (size_t)kr * 512 + (((lane & 15) ^ (kr & 7)) * 8),
                        Kd + (w * 16 + j * 4) * 128 + lane * 8);
            }
            #pragma unroll
            for (int j = 0; j < 4; j++) {
                int d = w * 32 + j * 8 + (lane >> 3);
                gload16(vp + (size_t)d * SEQ_L + (((lane & 7) ^ (d & 7)) * 8),
                        Vd + (w * 32 + j * 8) * 64 + lane * 8);
            }
        }
        // counted wait: prefetch loads stay in flight; current-tile loads done
        if (nkb >= 0) __builtin_amdgcn_s_waitcnt(0x0F78);   // vmcnt(8)
        else          __builtin_amdgcn_s_waitcnt(0x0F70);   // vmcnt(0)
        __builtin_amdgcn_s_barrier();           // everyone's staging landed

        const u16* K = Ks[bufc];
        const u16* V = Vs[bufc];

        // S^T = K Q^T over 64 keys: D[m = key = t*16+4*quad+r][n = q = ln]
        f32x4 accS[4] = {};
        #pragma unroll
        for (int s = 0; s < 4; s++)
            #pragma unroll
            for (int t = 0; t < 4; t++) {
                bf16x8 kf = *(const bf16x8*)(K + (t * 16 + ln) * 128 +
                                             (((4 * s + quad) ^ (ln & 7)) * 8));
                accS[t] = __builtin_amdgcn_mfma_f32_16x16x32_bf16(kf, qf[s], accS[t], 0, 0, 0);
            }

        // in-register online softmax for q-row = ln
        float mx = fmaxf(fmaxf(fmaxf(accS[0][0], accS[0][1]), fmaxf(accS[0][2], accS[0][3])),
                         fmaxf(fmaxf(fmaxf(accS[1][0], accS[1][1]), fmaxf(accS[1][2], accS[1][3])),
                               fmaxf(fmaxf(fmaxf(accS[2][0], accS[2][1]), fmaxf(accS[2][2], accS[2][3])),
                                     fmaxf(fmaxf(accS[3][0], accS[3][1]), fmaxf(accS[3][2], accS[3][3])))));
        mx = fmaxf(mx, __shfl_xor(mx, 16, 64));
        mx = fmaxf(mx, __shfl_xor(mx, 32, 64));
        float nm = fmaxf(m_st, mx * scale);
        float alpha = __expf(m_st - nm);
        m_st = nm;

        float p[4][4];
        float rs = 0.f;
        #pragma unroll
        for (int t = 0; t < 4; t++)
            #pragma unroll
            for (int r = 0; r < 4; r++) {
                p[t][r] = __expf(accS[t][r] * scale - nm);
                rs += p[t][r];
            }
        rs += __shfl_xor(rs, 16, 64);
        rs += __shfl_xor(rs, 32, 64);
        l_st = l_st * alpha + rs;

        // pack P^T to bf16 pairs: uA[t]=keys(4q'+0,1), uB[t]=keys(4q'+2,3) for q'=quad
        unsigned uA[4], uB[4];
        #pragma unroll
        for (int t = 0; t < 4; t++) {
            uA[t] = (unsigned)f2bf(p[t][0]) | ((unsigned)f2bf(p[t][1]) << 16);
            uB[t] = (unsigned)f2bf(p[t][2]) | ((unsigned)f2bf(p[t][3]) << 16);
        }

        // rescale accO by alpha (transposed to accO rows q = 4*quad+r)
        float al[4];
        #pragma unroll
        for (int r = 0; r < 4; r++) al[r] = __shfl(alpha, 4 * quad + r, 64);
        #pragma unroll
        for (int nt = 0; nt < 8; nt++)
            #pragma unroll
            for (int r = 0; r < 4; r++) accO[nt][r] *= al[r];

        // O += P V : build pf (A-op: lane holds P[q=ln][k=h*32+8*quad+j]) via shfl
        #pragma unroll
        for (int h = 0; h < 2; h++) {
            unsigned a0 = (unsigned)__shfl((int)uA[2 * h], srcA, 64);
            unsigned a1 = (unsigned)__shfl((int)uA[2 * h + 1], srcA, 64);
            unsigned b0 = (unsigned)__shfl((int)uB[2 * h], srcA, 64);
            unsigned b1 = (unsigned)__shfl((int)uB[2 * h + 1], srcA, 64);
            unsigned c0 = (unsigned)__shfl((int)uA[2 * h], srcB, 64);
            unsigned c1 = (unsigned)__shfl((int)uA[2 * h + 1], srcB, 64);
            unsigned d0 = (unsigned)__shfl((int)uB[2 * h], srcB, 64);
            unsigned d1 = (unsigned)__shfl((int)uB[2 * h + 1], srcB, 64);
            union { unsigned w4[4]; bf16x8 v; } pu;
            pu.w4[0] = hi ? a1 : a0;
            pu.w4[1] = hi ? b1 : b0;
            pu.w4[2] = hi ? c1 : c0;
            pu.w4[3] = hi ? d1 : d0;
            bf16x8 pf = pu.v;
            #pragma unroll
            for (int nt = 0; nt < 8; nt++) {
                bf16x8 vf = *(const bf16x8*)(V + (nt * 16 + ln) * 64 +
                                             (((4 * h + quad) ^ (ln & 7)) * 8));
                accO[nt] = __builtin_amdgcn_mfma_f32_16x16x32_bf16(pf, vf, accO[nt], 0, 0, 0);
            }
        }

        if (nkb < 0) break;
        __builtin_amdgcn_s_barrier();           // all reads of bufc done -> reusable
        bufc ^= 1;
    }

    // epilogue: attn_bf[row][ch*128 + col] = O / l  (l transposed to rows q=4*quad+r)
    float linv = 1.0f / fmaxf(l_st, 1e-20f);
    float inv[4];
    #pragma unroll
    for (int r = 0; r < 4; r++) inv[r] = __shfl(linv, 4 * quad + r, 64);
    #pragma unroll
    for (int nt = 0; nt < 8; nt++)
        #pragma unroll
        for (int r = 0; r < 4; r++)
            attn_bf[(size_t)(rowbase + 4 * quad + r) * 256 + ch * 128 + nt * 16 + ln]
                = f2bf(accO[nt][r] * inv[r]);
}

// ---------------- out projection: attn[16384,256](bf16) @ Wout^T + b -> fp32 halves ----------------
__global__ __launch_bounds__(256) void out_gemm(
    const u16* __restrict__ A, const u16* __restrict__ W, const float* __restrict__ bias,
    float* __restrict__ out) {
    __shared__ __align__(16) u16 As[64 * 64];
    __shared__ __align__(16) u16 Bs[64 * 64];
    int m0 = blockIdx.x * 64, n0 = blockIdx.y * 64;
    int tid = threadIdx.x, lane = tid & 63, w = tid >> 6;
    int ln = lane & 15, quad = lane >> 4;
    int lr8 = lane >> 3, lc = lane & 7;
    int swz_st = lc ^ (lr8 & 7);
    f32x4 acc[4] = {};
    for (int kk = 0; kk < 256; kk += 64) {
        __syncthreads();
        #pragma unroll
        for (int j = 0; j < 2; j++) {
            int r0 = w * 16 + j * 8;
            int r = r0 + lr8;
            gload16(A + (size_t)(m0 + r) * 256 + kk + swz_st * 8, As + r0 * 64 + lane * 8);
            gload16(W + (size_t)(n0 + r) * 256 + kk + swz_st * 8, Bs + r0 * 64 + lane * 8);
        }
        __syncthreads();
        #pragma unroll
        for (int s = 0; s < 2; s++) {
            int R = w * 16 + ln;
            bf16x8 af = *(const bf16x8*)(As + R * 64 + ((4 * s + quad) ^ (ln & 7)) * 8);
            #pragma unroll
            for (int t = 0; t < 4; t++) {
                int Rb = t * 16 + ln;
                bf16x8 bfr = *(const bf16x8*)(Bs + Rb * 64 + ((4 * s + quad) ^ (ln & 7)) * 8);
                acc[t] = __builtin_amdgcn_mfma_f32_16x16x32_bf16(af, bfr, acc[t], 0, 0, 0);
            }
        }
    }
    const size_t half = (size_t)M_TOT * 128;
    #pragma unroll
    for (int t = 0; t < 4; t++) {
        int col = n0 + t * 16 + ln;
        float bv = bias[col];
        float* base = (col < 128) ? (out + col) : (out + half + (col - 128));
        #pragma unroll
        for (int r = 0; r < 4; r++) {
            int row = m0 + w * 16 + 4 * quad + r;
            base[(size_t)row * 128] = acc[t][r] + bv;
        }
    }
}

extern "C" void kernel_launch(void* const* d_in, const int* in_sizes, int n_in,
                              void* d_out, int out_size, void* d_ws, size_t ws_size,
                              hipStream_t stream) {
    char* ws = (char*)d_ws;
    u16* x_bf    = (u16*)ws;                          // 16384*768  = 25.2 MB
    u16* qk_buf  = x_bf + (size_t)M_TOT * 768;        // 16384*512  = 16.8 MB
    u16* vt_buf  = qk_buf + (size_t)M_TOT * 512;      // 1024*4096  =  8.4 MB
    u16* attn_bf = vt_buf + (size_t)1024 * SEQ_L;     // 16384*256  =  8.4 MB
    u16* Wqkv_bf = attn_bf + (size_t)M_TOT * 256;     // 589824
    u16* Wout_bf = Wqkv_bf + 589824;                  // 65536
    unsigned long long* bmap = (unsigned long long*)(Wout_bf + 65536);   // 64 x u64

    hipLaunchKernelGGL(prep_all, dim3(6480), dim3(256), 0, stream,
                       (const float*)d_in[0], (const float*)d_in[1], (const float*)d_in[2],
                       (const float*)d_in[3], (const float*)d_in[4], (const float*)d_in[5],
                       (const float*)d_in[6], (const float*)d_in[8], d_in[10],
                       x_bf, Wqkv_bf, Wout_bf, bmap);
    hipLaunchKernelGGL(qkv_gemm, dim3(128, 6), dim3(256), 0, stream,
                       x_bf, Wqkv_bf, (const float*)d_in[7], qk_buf, vt_buf);
    hipLaunchKernelGGL(attn_sparse, dim3(512), dim3(256), 0, stream,
                       qk_buf, vt_buf, bmap, attn_bf);
    hipLaunchKernelGGL(out_gemm, dim3(256, 4), dim3(256), 0, stream,
                       attn_bf, Wout_bf, (const float*)d_in[9], (float*)d_out);
}